// Round 9
// baseline (207.973 us; speedup 1.0000x reference)
//
#include <hip/hip_runtime.h>
#include <hip/hip_fp16.h>
#include <math.h>

#define N_NODES 100000
#define N_EDGES 1600000
#define IN_F    128
#define OUT_F   64
#define K_BKT     196                            // dst buckets of 512 nodes
#define BKT_SHIFT 9
#define BKT_NODES 512
#define BKT_CAP   10240                          // slots per bucket (E~8163, +23 sigma)
#define QCAP      3072                           // slots per quarter (E~2041, +23 sigma)
#define CHUNK     4096                           // partition block edge count
#define PBLKS     ((N_EDGES + CHUNK - 1) / CHUNK)          // 391
#define LTILES    (N_NODES / 16)                 // 6250 exact 16-row MFMA tiles
#define LBLKS     ((LTILES + 3) / 4)             // 1563 (4 waves/block)

typedef _Float16 half8 __attribute__((ext_vector_type(8)));
typedef _Float16 h2 __attribute__((ext_vector_type(2)));
typedef _Float16 h4 __attribute__((ext_vector_type(4)));
typedef __fp16   q2v __attribute__((ext_vector_type(2)));
typedef float    f32x4 __attribute__((ext_vector_type(4)));

// f16 pair-dot with f32 accumulate (v_dot2_f32_f16); scalar fallback if absent.
__device__ __forceinline__ float fdot2f(h2 a, h2 b, float c) {
#if __has_builtin(__builtin_amdgcn_fdot2)
    return __builtin_amdgcn_fdot2(__builtin_bit_cast(q2v, a), __builtin_bit_cast(q2v, b), c, false);
#else
    return (float)a[0] * (float)b[0] + (float)a[1] * (float)b[1] + c;
#endif
}

// one v_add_f32_dpp step of a 16-lane xor-reduce (ctrl must be a literal)
#if __has_builtin(__builtin_amdgcn_update_dpp)
#define DPP_ADD(x, ctrl)                                                                  \
    (x) += __builtin_bit_cast(float, __builtin_amdgcn_update_dpp(                         \
               0, __builtin_bit_cast(int, (x)), (ctrl), 0xF, 0xF, true))
#define REDUCE16(x) do { DPP_ADD(x, 0xB1); DPP_ADD(x, 0x4E); \
                         DPP_ADD(x, 0x141); DPP_ADD(x, 0x140); } while (0)
#else
#define REDUCE16(x) do { x += __shfl_xor(x, 1); x += __shfl_xor(x, 2); \
                         x += __shfl_xor(x, 4); x += __shfl_xor(x, 8); } while (0)
#endif

// ---------------- workspace layout (4-byte units) ----------------
// fth      : N_NODES*OUT_F/2   fp16 projected features (12.8 MB)
// staging  : PBLKS*CHUNK uint  bucket-sorted edges, SLICE-contiguous per block
// pcnt     : PBLKS*256         per-block per-bucket counts
// pbase    : PBLKS*256         per-block per-bucket exclusive offsets
// (edge_src / row_beg / row_end deleted — CSR now lives in LDS of K23)

// K1 (UNCHANGED from r8): blocks [0,PBLKS): in-LDS counting sort of a
// 4096-edge chunk, dumped CONTIGUOUSLY into the block's staging slice;
// counts to pcnt/pbase. blocks [PBLKS,..): MFMA fp16 linear.
__global__ __launch_bounds__(256) void partition_linear_kernel(const int* __restrict__ src,
                                                               const int* __restrict__ dst,
                                                               unsigned* __restrict__ staging,
                                                               int* __restrict__ pcnt,
                                                               int* __restrict__ pbase,
                                                               const float* __restrict__ feat,
                                                               const float* __restrict__ W,
                                                               __half* __restrict__ fth) {
    __shared__ int hist[256], lbase[256], sc[256];
    __shared__ unsigned sval[CHUNK];
    int t = threadIdx.x;
    if (blockIdx.x < PBLKS) {
        hist[t] = 0;
        __syncthreads();
        int beg = blockIdx.x * CHUNK;
        int end = min(beg + CHUNK, N_EDGES);
        for (int i = beg + t; i < end; i += 256)
            atomicAdd(&hist[dst[i] >> BKT_SHIFT], 1);
        __syncthreads();
        int v = hist[t];
        sc[t] = v;
        __syncthreads();
        for (int off = 1; off < 256; off <<= 1) {
            int add = (t >= off) ? sc[t - off] : 0;
            __syncthreads();
            sc[t] += add;
            __syncthreads();
        }
        int lb = sc[t] - v;                      // block-local exclusive
        lbase[t] = lb;
        pcnt[blockIdx.x * 256 + t]  = v;
        pbase[blockIdx.x * 256 + t] = lb;
        hist[t] = 0;                             // reuse as rank counter
        __syncthreads();
        for (int i = beg + t; i < end; i += 256) {
            int s = src[i], d = dst[i];
            int b = d >> BKT_SHIFT;
            int r = atomicAdd(&hist[b], 1);
            sval[lbase[b] + r] = (unsigned)s | ((unsigned)(d & (BKT_NODES - 1)) << 17);
        }
        __syncthreads();
        int n = end - beg;
        for (int p = t; p < n; p += 256)
            staging[(size_t)blockIdx.x * CHUNK + p] = sval[p];
        return;
    }
    // ---- MFMA linear: one wave per 16-row tile ----
    int gwave = (blockIdx.x - PBLKS) * 4 + (t >> 6);
    if (gwave >= LTILES) return;
    int lane = t & 63;
    int m = lane & 15, kg = lane >> 4;
    int r0 = gwave * 16;

    half8 fb[4][4];
#pragma unroll
    for (int kb = 0; kb < 4; ++kb)
#pragma unroll
        for (int nb = 0; nb < 4; ++nb) {
            const float* wp = W + (size_t)(kb * 32 + kg * 8) * OUT_F + nb * 16 + m;
#pragma unroll
            for (int j = 0; j < 8; ++j)
                fb[kb][nb][j] = (_Float16)wp[j * OUT_F];
        }

    f32x4 acc[4];
#pragma unroll
    for (int nb = 0; nb < 4; ++nb) acc[nb] = (f32x4){0.f, 0.f, 0.f, 0.f};

#pragma unroll
    for (int kb = 0; kb < 4; ++kb) {
        const float4* ap = (const float4*)(feat + (size_t)(r0 + m) * IN_F + kb * 32 + kg * 8);
        float4 a0 = ap[0], a1 = ap[1];
        half8 fa = {(_Float16)a0.x, (_Float16)a0.y, (_Float16)a0.z, (_Float16)a0.w,
                    (_Float16)a1.x, (_Float16)a1.y, (_Float16)a1.z, (_Float16)a1.w};
#pragma unroll
        for (int nb = 0; nb < 4; ++nb)
            acc[nb] = __builtin_amdgcn_mfma_f32_16x16x32_f16(fa, fb[kb][nb], acc[nb], 0, 0, 0);
    }
#pragma unroll
    for (int nb = 0; nb < 4; ++nb)
#pragma unroll
        for (int i = 0; i < 4; ++i)
            fth[(size_t)(r0 + kg * 4 + i) * OUT_F + nb * 16 + m] = __float2half_rn(acc[nb][i]);
}

// K23: place + fused MERGED, one block per QUARTER-bucket (128 nodes).
// 784 blocks x 1024 thr = 2 blocks/CU (32 waves/CU, at cap) — fixes the
// granularity problem that sank the r2/r5 merges. Phases:
//   1. segment table for bucket b (pcnt/pbase column + 512-wide scan)
//   2. wave-per-segment gather of the whole bucket into sbuf (LDS)
//   3. count/scan/scatter ONLY this quarter's 128 nodes -> LDS CSR
//   4. fused phase: 16 waves x 8 nodes, identical math to r8's
//      fused_node_kernel but edge lists come from LDS (ds_read, not VMEM).
// Deletes: place->fused dispatch gap, global edge_src (8MB W + 8MB R),
// row_beg/row_end.
__global__ __launch_bounds__(1024) void place_fused_kernel(const unsigned* __restrict__ staging,
                                                           const int* __restrict__ pcnt,
                                                           const int* __restrict__ pbase,
                                                           const __half* __restrict__ fth,
                                                           float* __restrict__ out) {
    const float LOG2E = 1.44269504088896340736f;
    __shared__ unsigned sbuf[BKT_CAP];
    __shared__ int exo[PBLKS], pbs[PBLKS], scnt[PBLKS];
    __shared__ int s512[512];
    __shared__ int cnt[128], rbeg[128], lcur[128];
    __shared__ int csr[QCAP];
    __shared__ int ntot;
    int t = threadIdx.x;
    int b = blockIdx.x >> 2, qb = blockIdx.x & 3;

    // ---- phase 1: segment table ----
    int d = 0;
    if (t < PBLKS) { d = pcnt[t * 256 + b]; pbs[t] = pbase[t * 256 + b]; scnt[t] = d; }
    if (t < 512) s512[t] = (t < PBLKS) ? d : 0;
    if (t < 128) cnt[t] = 0;
    __syncthreads();
    for (int off = 1; off < 512; off <<= 1) {
        int add = (t >= off && t < 512) ? s512[t - off] : 0;
        __syncthreads();
        if (t < 512) s512[t] += add;
        __syncthreads();
    }
    if (t < PBLKS) exo[t] = s512[t] - d;
    if (t == PBLKS - 1) ntot = s512[t];
    __syncthreads();
    int n = ntot;

    // ---- phase 2: wave-per-segment gather of the whole bucket ----
    {
        int wid = t >> 6, ln = t & 63;
        for (int s = wid; s < PBLKS; s += 16) {
            int c = scnt[s], eo = exo[s];
            size_t gb = (size_t)s * CHUNK + pbs[s];
            for (int j = ln; j < c; j += 64)
                sbuf[eo + j] = staging[gb + j];
        }
    }
    __syncthreads();

    // ---- phase 3: quarter CSR in LDS ----
    for (int i = t; i < n; i += 1024) {
        int nl = sbuf[i] >> 17;
        if ((nl >> 7) == qb) atomicAdd(&cnt[nl & 127], 1);
    }
    __syncthreads();
    if (t < 128) s512[t] = cnt[t];               // reuse s512 for 128-scan
    __syncthreads();
    for (int off = 1; off < 128; off <<= 1) {
        int add = (t >= off && t < 128) ? s512[t - off] : 0;
        __syncthreads();
        if (t < 128) s512[t] += add;
        __syncthreads();
    }
    if (t < 128) { int v = cnt[t]; int b0 = s512[t] - v; rbeg[t] = b0; lcur[t] = b0; }
    __syncthreads();
    for (int i = t; i < n; i += 1024) {
        unsigned u = sbuf[i];
        int nl = u >> 17;
        if ((nl >> 7) == qb) {
            int pos = atomicAdd(&lcur[nl & 127], 1);
            csr[pos] = (int)(u & 0x1FFFFu);
        }
    }
    __syncthreads();

    // ---- phase 4: fused node computation (r8 math, LDS edge lists) ----
    int wid = t >> 6, lane = t & 63;
    int q = lane >> 4, ql = lane & 15;
    const _Float16* fh = (const _Float16*)fth;
#pragma unroll
    for (int k = 0; k < 8; ++k) {
        int ln = wid + 16 * k;                   // 16 waves x 8 nodes = 128
        int node = b * BKT_NODES + qb * 128 + ln;
        int beg = rbeg[ln];
        int end = beg + cnt[ln];

        h4 rdv = (node < N_NODES)
                   ? *(const h4*)(fh + (size_t)node * OUT_F + 4 * ql) : (h4){0, 0, 0, 0};
        h2 dlo = __builtin_shufflevector(rdv, rdv, 0, 1);
        h2 dhi = __builtin_shufflevector(rdv, rdv, 2, 3);

        float m = -1e30f, l = 0.f;
        float a0 = 0.f, a1 = 0.f, a2 = 0.f, a3 = 0.f;

        for (int i = beg; i < end; i += 16) {
            int e0 = i + q, e1 = e0 + 4, e2 = e0 + 8, e3 = e0 + 12;
            bool u0 = e0 < end, u1 = e1 < end, u2 = e2 < end, u3 = e3 < end;
            int s0 = csr[u0 ? e0 : beg];
            int s1 = csr[u1 ? e1 : beg];
            int s2 = csr[u2 ? e2 : beg];
            int s3 = csr[u3 ? e3 : beg];
            h4 rA = *(const h4*)(fh + (size_t)s0 * OUT_F + 4 * ql);
            h4 rB = *(const h4*)(fh + (size_t)s1 * OUT_F + 4 * ql);
            h4 rC = *(const h4*)(fh + (size_t)s2 * OUT_F + 4 * ql);
            h4 rD = *(const h4*)(fh + (size_t)s3 * OUT_F + 4 * ql);

            float p0 = fdot2f(__builtin_shufflevector(rA, rA, 0, 1), dlo,
                       fdot2f(__builtin_shufflevector(rA, rA, 2, 3), dhi, 0.f));
            float p1 = fdot2f(__builtin_shufflevector(rB, rB, 0, 1), dlo,
                       fdot2f(__builtin_shufflevector(rB, rB, 2, 3), dhi, 0.f));
            float p2 = fdot2f(__builtin_shufflevector(rC, rC, 0, 1), dlo,
                       fdot2f(__builtin_shufflevector(rC, rC, 2, 3), dhi, 0.f));
            float p3 = fdot2f(__builtin_shufflevector(rD, rD, 0, 1), dlo,
                       fdot2f(__builtin_shufflevector(rD, rD, 2, 3), dhi, 0.f));
            REDUCE16(p0);
            REDUCE16(p1);
            REDUCE16(p2);
            REDUCE16(p3);
            p0 = u0 ? p0 * LOG2E : -1e30f;
            p1 = u1 ? p1 * LOG2E : -1e30f;
            p2 = u2 ? p2 * LOG2E : -1e30f;
            p3 = u3 ? p3 * LOG2E : -1e30f;

            float nm = fmaxf(fmaxf(fmaxf(p0, p1), fmaxf(p2, p3)), m);
            float alpha = exp2f(m - nm);
            float w0 = exp2f(p0 - nm), w1 = exp2f(p1 - nm);
            float w2 = exp2f(p2 - nm), w3 = exp2f(p3 - nm);
            l = l * alpha + ((w0 + w1) + (w2 + w3));
#if __has_builtin(__builtin_amdgcn_cvt_pkrtz)
            h2 wlo = __builtin_bit_cast(h2, __builtin_amdgcn_cvt_pkrtz(w0, w1));
            h2 whi = __builtin_bit_cast(h2, __builtin_amdgcn_cvt_pkrtz(w2, w3));
#else
            h2 wlo = {(_Float16)w0, (_Float16)w1};
            h2 whi = {(_Float16)w2, (_Float16)w3};
#endif
            h2 cab0 = {rA[0], rB[0]}, ccd0 = {rC[0], rD[0]};
            h2 cab1 = {rA[1], rB[1]}, ccd1 = {rC[1], rD[1]};
            h2 cab2 = {rA[2], rB[2]}, ccd2 = {rC[2], rD[2]};
            h2 cab3 = {rA[3], rB[3]}, ccd3 = {rC[3], rD[3]};
            a0 = fdot2f(wlo, cab0, fdot2f(whi, ccd0, a0 * alpha));
            a1 = fdot2f(wlo, cab1, fdot2f(whi, ccd1, a1 * alpha));
            a2 = fdot2f(wlo, cab2, fdot2f(whi, ccd2, a2 * alpha));
            a3 = fdot2f(wlo, cab3, fdot2f(whi, ccd3, a3 * alpha));
            m = nm;
        }

        // merge the 4 quarter-states (xor16, then xor32) in log2 domain
#pragma unroll
        for (int dd = 16; dd <= 32; dd <<= 1) {
            float m2 = __shfl_xor(m, dd), l2 = __shfl_xor(l, dd);
            float b0 = __shfl_xor(a0, dd), b1 = __shfl_xor(a1, dd);
            float b2 = __shfl_xor(a2, dd), b3 = __shfl_xor(a3, dd);
            float M = fmaxf(m, m2);
            float e1 = exp2f(m - M), e2 = exp2f(m2 - M);
            l = l * e1 + l2 * e2;
            a0 = a0 * e1 + b0 * e2;
            a1 = a1 * e1 + b1 * e2;
            a2 = a2 * e1 + b2 * e2;
            a3 = a3 * e1 + b3 * e2;
            m = M;
        }
        if (q == 0 && node < N_NODES) {
            float inv = (l > 0.f) ? 1.f / l : 0.f;
            *(float4*)(out + (size_t)node * OUT_F + 4 * ql) =
                make_float4(a0 * inv, a1 * inv, a2 * inv, a3 * inv);
        }
    }
}

extern "C" void kernel_launch(void* const* d_in, const int* in_sizes, int n_in,
                              void* d_out, int out_size, void* d_ws, size_t ws_size,
                              hipStream_t stream) {
    const float* feat = (const float*)d_in[0];
    const float* W    = (const float*)d_in[1];
    const int*   src  = (const int*)d_in[2];
    const int*   dst  = (const int*)d_in[3];
    float* out = (float*)d_out;

    __half*   fth      = (__half*)d_ws;
    unsigned* staging  = (unsigned*)((int*)d_ws + (size_t)N_NODES * OUT_F / 2);
    int*      pcnt     = (int*)(staging + (size_t)PBLKS * CHUNK);
    int*      pbase    = pcnt + PBLKS * 256;

    partition_linear_kernel<<<PBLKS + LBLKS, 256, 0, stream>>>(src, dst, staging, pcnt, pbase,
                                                               feat, W, fth);
    place_fused_kernel<<<K_BKT * 4, 1024, 0, stream>>>(staging, pcnt, pbase, fth, out);
}

// Round 10
// 188.410 us; speedup vs baseline: 1.1038x; 1.1038x over previous
//
#include <hip/hip_runtime.h>
#include <hip/hip_fp16.h>
#include <math.h>

#define N_NODES 100000
#define N_EDGES 1600000
#define IN_F    128
#define OUT_F   64
#define NQ        782                            // quarter-buckets of 128 nodes
#define Q_SHIFT   7
#define Q_NODES   128
#define QCAP      3072                           // slots per quarter (mean 2048, +22 sigma)
#define CHUNK     4096                           // partition block edge count
#define PBLKS     ((N_EDGES + CHUNK - 1) / CHUNK)          // 391
#define LTILES    (N_NODES / 16)                 // 6250 exact 16-row MFMA tiles
#define LBLKS     ((LTILES + 3) / 4)             // 1563 (4 waves/block)

typedef _Float16 half8 __attribute__((ext_vector_type(8)));
typedef _Float16 h2 __attribute__((ext_vector_type(2)));
typedef _Float16 h4 __attribute__((ext_vector_type(4)));
typedef __fp16   q2v __attribute__((ext_vector_type(2)));
typedef float    f32x4 __attribute__((ext_vector_type(4)));

// f16 pair-dot with f32 accumulate (v_dot2_f32_f16); scalar fallback if absent.
__device__ __forceinline__ float fdot2f(h2 a, h2 b, float c) {
#if __has_builtin(__builtin_amdgcn_fdot2)
    return __builtin_amdgcn_fdot2(__builtin_bit_cast(q2v, a), __builtin_bit_cast(q2v, b), c, false);
#else
    return (float)a[0] * (float)b[0] + (float)a[1] * (float)b[1] + c;
#endif
}

// one v_add_f32_dpp step of a 16-lane xor-reduce (ctrl must be a literal)
#if __has_builtin(__builtin_amdgcn_update_dpp)
#define DPP_ADD(x, ctrl)                                                                  \
    (x) += __builtin_bit_cast(float, __builtin_amdgcn_update_dpp(                         \
               0, __builtin_bit_cast(int, (x)), (ctrl), 0xF, 0xF, true))
#define REDUCE16(x) do { DPP_ADD(x, 0xB1); DPP_ADD(x, 0x4E); \
                         DPP_ADD(x, 0x141); DPP_ADD(x, 0x140); } while (0)
#else
#define REDUCE16(x) do { x += __shfl_xor(x, 1); x += __shfl_xor(x, 2); \
                         x += __shfl_xor(x, 4); x += __shfl_xor(x, 8); } while (0)
#endif

// ---------------- workspace layout (4-byte units) ----------------
// fth      : N_NODES*OUT_F/2   fp16 projected features (12.8 MB)
// staging  : PBLKS*CHUNK uint  quarter-sorted edges, SLICE-contiguous per block
// pcnt     : PBLKS*1024        per-block per-quarter counts
// pbase    : PBLKS*1024        per-block per-quarter exclusive offsets
//
// r9 post-mortem: quarter-blocks each redid the WHOLE bucket's segment
// table + gather (4x duplication ~ 85us). Fix: K1 sorts into 1024
// quarter-bins directly, so each K23 block touches only its own ~2041
// edges. K23 phase 4 (fused math from LDS CSR) is r9's verified code.

// K1: blocks [0,PBLKS): in-LDS counting sort of a 4096-edge chunk into
//     1024 quarter-bins (4 bins/thread scan), dumped CONTIGUOUSLY into the
//     block's staging slice; counts/offsets to pcnt/pbase (int4 writes).
//     blocks [PBLKS,..): MFMA fp16 linear — wave = 16-row tile of feat @ W.
__global__ __launch_bounds__(256) void partition_linear_kernel(const int* __restrict__ src,
                                                               const int* __restrict__ dst,
                                                               unsigned* __restrict__ staging,
                                                               int* __restrict__ pcnt,
                                                               int* __restrict__ pbase,
                                                               const float* __restrict__ feat,
                                                               const float* __restrict__ W,
                                                               __half* __restrict__ fth) {
    __shared__ int hist[1024], lbase[1024], sc[256];
    __shared__ unsigned sval[CHUNK];
    int t = threadIdx.x;
    if (blockIdx.x < PBLKS) {
        hist[t] = 0; hist[t + 256] = 0; hist[t + 512] = 0; hist[t + 768] = 0;
        __syncthreads();
        int beg = blockIdx.x * CHUNK;
        int end = min(beg + CHUNK, N_EDGES);
        for (int i = beg + t; i < end; i += 256)
            atomicAdd(&hist[dst[i] >> Q_SHIFT], 1);
        __syncthreads();
        int h0 = hist[4 * t], h1 = hist[4 * t + 1], h2i = hist[4 * t + 2], h3 = hist[4 * t + 3];
        int tot = h0 + h1 + h2i + h3;
        sc[t] = tot;
        __syncthreads();
        for (int off = 1; off < 256; off <<= 1) {
            int add = (t >= off) ? sc[t - off] : 0;
            __syncthreads();
            sc[t] += add;
            __syncthreads();
        }
        int excl = sc[t] - tot;                  // block-local exclusive over 4t
        int b0 = excl, b1 = excl + h0, b2 = b1 + h1, b3 = b2 + h2i;
        lbase[4 * t] = b0; lbase[4 * t + 1] = b1; lbase[4 * t + 2] = b2; lbase[4 * t + 3] = b3;
        *(int4*)(pcnt  + (size_t)blockIdx.x * 1024 + 4 * t) = make_int4(h0, h1, h2i, h3);
        *(int4*)(pbase + (size_t)blockIdx.x * 1024 + 4 * t) = make_int4(b0, b1, b2, b3);
        hist[4 * t] = 0; hist[4 * t + 1] = 0; hist[4 * t + 2] = 0; hist[4 * t + 3] = 0;
        __syncthreads();
        for (int i = beg + t; i < end; i += 256) {
            int s = src[i], d = dst[i];
            int b = d >> Q_SHIFT;
            int r = atomicAdd(&hist[b], 1);
            sval[lbase[b] + r] = (unsigned)s | ((unsigned)(d & (Q_NODES - 1)) << 17);
        }
        __syncthreads();
        int n = end - beg;
        for (int p = t; p < n; p += 256)
            staging[(size_t)blockIdx.x * CHUNK + p] = sval[p];
        return;
    }
    // ---- MFMA linear: one wave per 16-row tile ----
    int gwave = (blockIdx.x - PBLKS) * 4 + (t >> 6);
    if (gwave >= LTILES) return;
    int lane = t & 63;
    int m = lane & 15, kg = lane >> 4;
    int r0 = gwave * 16;

    half8 fb[4][4];
#pragma unroll
    for (int kb = 0; kb < 4; ++kb)
#pragma unroll
        for (int nb = 0; nb < 4; ++nb) {
            const float* wp = W + (size_t)(kb * 32 + kg * 8) * OUT_F + nb * 16 + m;
#pragma unroll
            for (int j = 0; j < 8; ++j)
                fb[kb][nb][j] = (_Float16)wp[j * OUT_F];
        }

    f32x4 acc[4];
#pragma unroll
    for (int nb = 0; nb < 4; ++nb) acc[nb] = (f32x4){0.f, 0.f, 0.f, 0.f};

#pragma unroll
    for (int kb = 0; kb < 4; ++kb) {
        const float4* ap = (const float4*)(feat + (size_t)(r0 + m) * IN_F + kb * 32 + kg * 8);
        float4 a0 = ap[0], a1 = ap[1];
        half8 fa = {(_Float16)a0.x, (_Float16)a0.y, (_Float16)a0.z, (_Float16)a0.w,
                    (_Float16)a1.x, (_Float16)a1.y, (_Float16)a1.z, (_Float16)a1.w};
#pragma unroll
        for (int nb = 0; nb < 4; ++nb)
            acc[nb] = __builtin_amdgcn_mfma_f32_16x16x32_f16(fa, fb[kb][nb], acc[nb], 0, 0, 0);
    }
#pragma unroll
    for (int nb = 0; nb < 4; ++nb)
#pragma unroll
        for (int i = 0; i < 4; ++i)
            fth[(size_t)(r0 + kg * 4 + i) * OUT_F + nb * 16 + m] = __float2half_rn(acc[nb][i]);
}

// K23: one block per QUARTER (128 nodes), 1024 thr, 782 blocks (2/CU).
//   1. segment table: pcnt/pbase column q + 512-wide scan over 391 segments
//   2. gather: 8 lanes per segment (~5 edges each) into sbuf
//   3. count/scan/scatter 128 nodes -> LDS CSR (~2041 edges)
//   4. fused phase (r9-verified): 16 waves x 8 nodes, edge lists from LDS.
__global__ __launch_bounds__(1024) void quarter_fused_kernel(const unsigned* __restrict__ staging,
                                                             const int* __restrict__ pcnt,
                                                             const int* __restrict__ pbase,
                                                             const __half* __restrict__ fth,
                                                             float* __restrict__ out) {
    const float LOG2E = 1.44269504088896340736f;
    __shared__ unsigned sbuf[QCAP];
    __shared__ int csr[QCAP];
    __shared__ int exo[PBLKS], pbs[PBLKS], scnt[PBLKS];
    __shared__ int s512[512];
    __shared__ int cnt[Q_NODES], rbeg[Q_NODES], lcur[Q_NODES];
    __shared__ int ntot;
    int t = threadIdx.x;
    int qq = blockIdx.x;

    // ---- phase 1: segment table ----
    int d = 0;
    if (t < PBLKS) { d = pcnt[(size_t)t * 1024 + qq]; pbs[t] = pbase[(size_t)t * 1024 + qq]; scnt[t] = d; }
    if (t < 512) s512[t] = (t < PBLKS) ? d : 0;
    if (t < Q_NODES) cnt[t] = 0;
    __syncthreads();
    for (int off = 1; off < 512; off <<= 1) {
        int add = (t >= off && t < 512) ? s512[t - off] : 0;
        __syncthreads();
        if (t < 512) s512[t] += add;
        __syncthreads();
    }
    if (t < PBLKS) exo[t] = s512[t] - d;
    if (t == PBLKS - 1) ntot = s512[t];
    __syncthreads();
    int n = ntot;

    // ---- phase 2: gather, 8 lanes per segment (~5.2 edges avg) ----
    {
        int wid = t >> 6, ln = t & 63;
        int sg0 = wid * 8 + (ln >> 3), j0 = ln & 7;
        for (int s = sg0; s < PBLKS; s += 128) {
            int c = scnt[s], eo = exo[s];
            size_t gb = (size_t)s * CHUNK + pbs[s];
            for (int j = j0; j < c; j += 8)
                sbuf[eo + j] = staging[gb + j];
        }
    }
    __syncthreads();

    // ---- phase 3: quarter CSR in LDS ----
    for (int i = t; i < n; i += 1024)
        atomicAdd(&cnt[sbuf[i] >> 17], 1);
    __syncthreads();
    if (t < Q_NODES) s512[t] = cnt[t];
    __syncthreads();
    for (int off = 1; off < Q_NODES; off <<= 1) {
        int add = (t >= off && t < Q_NODES) ? s512[t - off] : 0;
        __syncthreads();
        if (t < Q_NODES) s512[t] += add;
        __syncthreads();
    }
    if (t < Q_NODES) { int v = cnt[t]; int b0 = s512[t] - v; rbeg[t] = b0; lcur[t] = b0; }
    __syncthreads();
    for (int i = t; i < n; i += 1024) {
        unsigned u = sbuf[i];
        int pos = atomicAdd(&lcur[u >> 17], 1);
        csr[pos] = (int)(u & 0x1FFFFu);
    }
    __syncthreads();

    // ---- phase 4: fused node computation (r9-verified, LDS edge lists) ----
    int wid = t >> 6, lane = t & 63;
    int q = lane >> 4, ql = lane & 15;
    const _Float16* fh = (const _Float16*)fth;
#pragma unroll
    for (int k = 0; k < 8; ++k) {
        int ln = wid + 16 * k;                   // 16 waves x 8 nodes = 128
        int node = qq * Q_NODES + ln;
        int beg = rbeg[ln];
        int end = beg + cnt[ln];

        h4 rdv = (node < N_NODES)
                   ? *(const h4*)(fh + (size_t)node * OUT_F + 4 * ql) : (h4){0, 0, 0, 0};
        h2 dlo = __builtin_shufflevector(rdv, rdv, 0, 1);
        h2 dhi = __builtin_shufflevector(rdv, rdv, 2, 3);

        float m = -1e30f, l = 0.f;
        float a0 = 0.f, a1 = 0.f, a2 = 0.f, a3 = 0.f;

        for (int i = beg; i < end; i += 16) {
            int e0 = i + q, e1 = e0 + 4, e2 = e0 + 8, e3 = e0 + 12;
            bool u0 = e0 < end, u1 = e1 < end, u2 = e2 < end, u3 = e3 < end;
            int s0 = csr[u0 ? e0 : beg];
            int s1 = csr[u1 ? e1 : beg];
            int s2 = csr[u2 ? e2 : beg];
            int s3 = csr[u3 ? e3 : beg];
            h4 rA = *(const h4*)(fh + (size_t)s0 * OUT_F + 4 * ql);
            h4 rB = *(const h4*)(fh + (size_t)s1 * OUT_F + 4 * ql);
            h4 rC = *(const h4*)(fh + (size_t)s2 * OUT_F + 4 * ql);
            h4 rD = *(const h4*)(fh + (size_t)s3 * OUT_F + 4 * ql);

            float p0 = fdot2f(__builtin_shufflevector(rA, rA, 0, 1), dlo,
                       fdot2f(__builtin_shufflevector(rA, rA, 2, 3), dhi, 0.f));
            float p1 = fdot2f(__builtin_shufflevector(rB, rB, 0, 1), dlo,
                       fdot2f(__builtin_shufflevector(rB, rB, 2, 3), dhi, 0.f));
            float p2 = fdot2f(__builtin_shufflevector(rC, rC, 0, 1), dlo,
                       fdot2f(__builtin_shufflevector(rC, rC, 2, 3), dhi, 0.f));
            float p3 = fdot2f(__builtin_shufflevector(rD, rD, 0, 1), dlo,
                       fdot2f(__builtin_shufflevector(rD, rD, 2, 3), dhi, 0.f));
            REDUCE16(p0);
            REDUCE16(p1);
            REDUCE16(p2);
            REDUCE16(p3);
            p0 = u0 ? p0 * LOG2E : -1e30f;
            p1 = u1 ? p1 * LOG2E : -1e30f;
            p2 = u2 ? p2 * LOG2E : -1e30f;
            p3 = u3 ? p3 * LOG2E : -1e30f;

            float nm = fmaxf(fmaxf(fmaxf(p0, p1), fmaxf(p2, p3)), m);
            float alpha = exp2f(m - nm);
            float w0 = exp2f(p0 - nm), w1 = exp2f(p1 - nm);
            float w2 = exp2f(p2 - nm), w3 = exp2f(p3 - nm);
            l = l * alpha + ((w0 + w1) + (w2 + w3));
#if __has_builtin(__builtin_amdgcn_cvt_pkrtz)
            h2 wlo = __builtin_bit_cast(h2, __builtin_amdgcn_cvt_pkrtz(w0, w1));
            h2 whi = __builtin_bit_cast(h2, __builtin_amdgcn_cvt_pkrtz(w2, w3));
#else
            h2 wlo = {(_Float16)w0, (_Float16)w1};
            h2 whi = {(_Float16)w2, (_Float16)w3};
#endif
            h2 cab0 = {rA[0], rB[0]}, ccd0 = {rC[0], rD[0]};
            h2 cab1 = {rA[1], rB[1]}, ccd1 = {rC[1], rD[1]};
            h2 cab2 = {rA[2], rB[2]}, ccd2 = {rC[2], rD[2]};
            h2 cab3 = {rA[3], rB[3]}, ccd3 = {rC[3], rD[3]};
            a0 = fdot2f(wlo, cab0, fdot2f(whi, ccd0, a0 * alpha));
            a1 = fdot2f(wlo, cab1, fdot2f(whi, ccd1, a1 * alpha));
            a2 = fdot2f(wlo, cab2, fdot2f(whi, ccd2, a2 * alpha));
            a3 = fdot2f(wlo, cab3, fdot2f(whi, ccd3, a3 * alpha));
            m = nm;
        }

        // merge the 4 quarter-states (xor16, then xor32) in log2 domain
#pragma unroll
        for (int dd = 16; dd <= 32; dd <<= 1) {
            float m2 = __shfl_xor(m, dd), l2 = __shfl_xor(l, dd);
            float b0 = __shfl_xor(a0, dd), b1 = __shfl_xor(a1, dd);
            float b2 = __shfl_xor(a2, dd), b3 = __shfl_xor(a3, dd);
            float M = fmaxf(m, m2);
            float e1 = exp2f(m - M), e2 = exp2f(m2 - M);
            l = l * e1 + l2 * e2;
            a0 = a0 * e1 + b0 * e2;
            a1 = a1 * e1 + b1 * e2;
            a2 = a2 * e1 + b2 * e2;
            a3 = a3 * e1 + b3 * e2;
            m = M;
        }
        if (q == 0 && node < N_NODES) {
            float inv = (l > 0.f) ? 1.f / l : 0.f;
            *(float4*)(out + (size_t)node * OUT_F + 4 * ql) =
                make_float4(a0 * inv, a1 * inv, a2 * inv, a3 * inv);
        }
    }
}

extern "C" void kernel_launch(void* const* d_in, const int* in_sizes, int n_in,
                              void* d_out, int out_size, void* d_ws, size_t ws_size,
                              hipStream_t stream) {
    const float* feat = (const float*)d_in[0];
    const float* W    = (const float*)d_in[1];
    const int*   src  = (const int*)d_in[2];
    const int*   dst  = (const int*)d_in[3];
    float* out = (float*)d_out;

    __half*   fth      = (__half*)d_ws;
    unsigned* staging  = (unsigned*)((int*)d_ws + (size_t)N_NODES * OUT_F / 2);
    int*      pcnt     = (int*)(staging + (size_t)PBLKS * CHUNK);
    int*      pbase    = pcnt + (size_t)PBLKS * 1024;

    partition_linear_kernel<<<PBLKS + LBLKS, 256, 0, stream>>>(src, dst, staging, pcnt, pbase,
                                                               feat, W, fth);
    quarter_fused_kernel<<<NQ, 1024, 0, stream>>>(staging, pcnt, pbase, fth, out);
}

// Round 11
// 178.608 us; speedup vs baseline: 1.1644x; 1.0549x over previous
//
#include <hip/hip_runtime.h>
#include <hip/hip_fp16.h>
#include <math.h>

#define N_NODES 100000
#define N_EDGES 1600000
#define IN_F    128
#define OUT_F   64
#define NQ        782                            // quarter-buckets of 128 nodes
#define Q_SHIFT   7
#define Q_NODES   128
#define QCAP      3072                           // slots per quarter (mean 2048, +22 sigma)
#define CHUNK     4096                           // partition block edge count
#define PBLKS     ((N_EDGES + CHUNK - 1) / CHUNK)          // 391
#define LTILES    (N_NODES / 16)                 // 6250 exact 16-row MFMA tiles
#define LBLKS     ((LTILES + 3) / 4)             // 1563 (4 waves/block)

typedef _Float16 half8 __attribute__((ext_vector_type(8)));
typedef _Float16 h2 __attribute__((ext_vector_type(2)));
typedef _Float16 h4 __attribute__((ext_vector_type(4)));
typedef __fp16   q2v __attribute__((ext_vector_type(2)));
typedef float    f32x4 __attribute__((ext_vector_type(4)));

// f16 pair-dot with f32 accumulate (v_dot2_f32_f16); scalar fallback if absent.
__device__ __forceinline__ float fdot2f(h2 a, h2 b, float c) {
#if __has_builtin(__builtin_amdgcn_fdot2)
    return __builtin_amdgcn_fdot2(__builtin_bit_cast(q2v, a), __builtin_bit_cast(q2v, b), c, false);
#else
    return (float)a[0] * (float)b[0] + (float)a[1] * (float)b[1] + c;
#endif
}

// one v_add_f32_dpp step of a 16-lane xor-reduce (ctrl must be a literal)
#if __has_builtin(__builtin_amdgcn_update_dpp)
#define DPP_ADD(x, ctrl)                                                                  \
    (x) += __builtin_bit_cast(float, __builtin_amdgcn_update_dpp(                         \
               0, __builtin_bit_cast(int, (x)), (ctrl), 0xF, 0xF, true))
#define REDUCE16(x) do { DPP_ADD(x, 0xB1); DPP_ADD(x, 0x4E); \
                         DPP_ADD(x, 0x141); DPP_ADD(x, 0x140); } while (0)
#else
#define REDUCE16(x) do { x += __shfl_xor(x, 1); x += __shfl_xor(x, 2); \
                         x += __shfl_xor(x, 4); x += __shfl_xor(x, 8); } while (0)
#endif

// ---------------- workspace layout (4-byte units) ----------------
// fth      : N_NODES*OUT_F/2   fp16 projected features (12.8 MB)
// staging  : PBLKS*CHUNK uint  quarter-sorted edges, SLICE-contiguous per block
// pmeta    : PBLKS*1024        packed (count<<16 | base) per block per quarter
//
// r10 post-mortem: K23's phases cost ~25us — 32 block-wide barriers (two
// Hillis scans), a redundant count pass, and 2x391 scattered metadata
// column reads. This version: wave-0 shfl scans (4 barriers total), count
// fused into gather, packed single-uint metadata.

// K1: blocks [0,PBLKS): in-LDS counting sort of a 4096-edge chunk into
//     1024 quarter-bins, dumped CONTIGUOUSLY into the block's staging
//     slice; packed (cnt<<16|base) to pmeta (int4 writes).
//     blocks [PBLKS,..): MFMA fp16 linear — wave = 16-row tile of feat @ W.
__global__ __launch_bounds__(256) void partition_linear_kernel(const int* __restrict__ src,
                                                               const int* __restrict__ dst,
                                                               unsigned* __restrict__ staging,
                                                               unsigned* __restrict__ pmeta,
                                                               const float* __restrict__ feat,
                                                               const float* __restrict__ W,
                                                               __half* __restrict__ fth) {
    __shared__ int hist[1024], lbase[1024], sc[256];
    __shared__ unsigned sval[CHUNK];
    int t = threadIdx.x;
    if (blockIdx.x < PBLKS) {
        hist[t] = 0; hist[t + 256] = 0; hist[t + 512] = 0; hist[t + 768] = 0;
        __syncthreads();
        int beg = blockIdx.x * CHUNK;
        int end = min(beg + CHUNK, N_EDGES);
        for (int i = beg + t; i < end; i += 256)
            atomicAdd(&hist[dst[i] >> Q_SHIFT], 1);
        __syncthreads();
        int h0 = hist[4 * t], h1 = hist[4 * t + 1], h2i = hist[4 * t + 2], h3 = hist[4 * t + 3];
        int tot = h0 + h1 + h2i + h3;
        sc[t] = tot;
        __syncthreads();
        for (int off = 1; off < 256; off <<= 1) {
            int add = (t >= off) ? sc[t - off] : 0;
            __syncthreads();
            sc[t] += add;
            __syncthreads();
        }
        int excl = sc[t] - tot;                  // block-local exclusive over 4t
        int b0 = excl, b1 = excl + h0, b2 = b1 + h1, b3 = b2 + h2i;
        lbase[4 * t] = b0; lbase[4 * t + 1] = b1; lbase[4 * t + 2] = b2; lbase[4 * t + 3] = b3;
        *(uint4*)(pmeta + (size_t)blockIdx.x * 1024 + 4 * t) =
            make_uint4(((unsigned)h0 << 16) | b0, ((unsigned)h1 << 16) | b1,
                       ((unsigned)h2i << 16) | b2, ((unsigned)h3 << 16) | b3);
        hist[4 * t] = 0; hist[4 * t + 1] = 0; hist[4 * t + 2] = 0; hist[4 * t + 3] = 0;
        __syncthreads();
        for (int i = beg + t; i < end; i += 256) {
            int s = src[i], d = dst[i];
            int b = d >> Q_SHIFT;
            int r = atomicAdd(&hist[b], 1);
            sval[lbase[b] + r] = (unsigned)s | ((unsigned)(d & (Q_NODES - 1)) << 17);
        }
        __syncthreads();
        int n = end - beg;
        for (int p = t; p < n; p += 256)
            staging[(size_t)blockIdx.x * CHUNK + p] = sval[p];
        return;
    }
    // ---- MFMA linear: one wave per 16-row tile ----
    int gwave = (blockIdx.x - PBLKS) * 4 + (t >> 6);
    if (gwave >= LTILES) return;
    int lane = t & 63;
    int m = lane & 15, kg = lane >> 4;
    int r0 = gwave * 16;

    half8 fb[4][4];
#pragma unroll
    for (int kb = 0; kb < 4; ++kb)
#pragma unroll
        for (int nb = 0; nb < 4; ++nb) {
            const float* wp = W + (size_t)(kb * 32 + kg * 8) * OUT_F + nb * 16 + m;
#pragma unroll
            for (int j = 0; j < 8; ++j)
                fb[kb][nb][j] = (_Float16)wp[j * OUT_F];
        }

    f32x4 acc[4];
#pragma unroll
    for (int nb = 0; nb < 4; ++nb) acc[nb] = (f32x4){0.f, 0.f, 0.f, 0.f};

#pragma unroll
    for (int kb = 0; kb < 4; ++kb) {
        const float4* ap = (const float4*)(feat + (size_t)(r0 + m) * IN_F + kb * 32 + kg * 8);
        float4 a0 = ap[0], a1 = ap[1];
        half8 fa = {(_Float16)a0.x, (_Float16)a0.y, (_Float16)a0.z, (_Float16)a0.w,
                    (_Float16)a1.x, (_Float16)a1.y, (_Float16)a1.z, (_Float16)a1.w};
#pragma unroll
        for (int nb = 0; nb < 4; ++nb)
            acc[nb] = __builtin_amdgcn_mfma_f32_16x16x32_f16(fa, fb[kb][nb], acc[nb], 0, 0, 0);
    }
#pragma unroll
    for (int nb = 0; nb < 4; ++nb)
#pragma unroll
        for (int i = 0; i < 4; ++i)
            fth[(size_t)(r0 + kg * 4 + i) * OUT_F + nb * 16 + m] = __float2half_rn(acc[nb][i]);
}

// K23: one block per QUARTER (128 nodes), 1024 thr, 782 blocks (2/CU).
//   1. t<391 load packed meta -> LDS; wave 0 shfl-scans the 391 counts
//      (7/lane serial + 6-step shfl_up) -> exo. 2 barriers, no Hillis.
//   2. gather (8 lanes/segment) with per-node count fused into the pass.
//   3. wave 0 shfl-scans 128 node counts -> rbeg/lcur; scatter to LDS CSR.
//   4. fused phase: 16 waves x 8 nodes, r10-verified math; m is
//      wave-uniform so the rescale is a uniform branch and the epilogue
//      merge is plain shfl-adds (no exp2).
__global__ __launch_bounds__(1024) void quarter_fused_kernel(const unsigned* __restrict__ staging,
                                                             const unsigned* __restrict__ pmeta,
                                                             const __half* __restrict__ fth,
                                                             float* __restrict__ out) {
    const float LOG2E = 1.44269504088896340736f;
    __shared__ unsigned sbuf[QCAP];
    __shared__ int csr[QCAP];
    __shared__ unsigned smeta[PBLKS];
    __shared__ int exo[PBLKS];
    __shared__ int cnt[Q_NODES], rbeg[Q_NODES], lcur[Q_NODES];
    __shared__ int ntot;
    int t = threadIdx.x;
    int qq = blockIdx.x;

    // ---- phase 1: metadata + wave-0 segment scan ----
    if (t < PBLKS) smeta[t] = pmeta[(size_t)t * 1024 + qq];
    if (t < Q_NODES) cnt[t] = 0;
    __syncthreads();
    if (t < 64) {
        int s0 = t * 7;
        int loc[7];
        int sum = 0;
#pragma unroll
        for (int j = 0; j < 7; ++j) {
            int s = s0 + j;
            int v = (s < PBLKS) ? (int)(smeta[s] >> 16) : 0;
            loc[j] = sum;
            sum += v;
        }
        int inc = sum;
#pragma unroll
        for (int d = 1; d < 64; d <<= 1) {
            int o = __shfl_up(inc, d);
            if (t >= d) inc += o;
        }
        int excl = inc - sum;
#pragma unroll
        for (int j = 0; j < 7; ++j)
            if (s0 + j < PBLKS) exo[s0 + j] = excl + loc[j];
        if (t == 63) ntot = inc;
    }
    __syncthreads();
    int n = ntot;

    // ---- phase 2: gather (8 lanes/segment) + fused per-node count ----
    {
        int wid = t >> 6, ln = t & 63;
        int sg0 = wid * 8 + (ln >> 3), j0 = ln & 7;
        for (int s = sg0; s < PBLKS; s += 128) {
            unsigned meta = smeta[s];
            int c = (int)(meta >> 16), pb = (int)(meta & 0xFFFFu);
            int eo = exo[s];
            size_t gb = (size_t)s * CHUNK + pb;
            for (int j = j0; j < c; j += 8) {
                unsigned u = staging[gb + j];
                sbuf[eo + j] = u;
                atomicAdd(&cnt[u >> 17], 1);
            }
        }
    }
    __syncthreads();

    // ---- phase 3: wave-0 node scan + scatter to CSR ----
    if (t < 64) {
        int c0 = cnt[2 * t], c1 = cnt[2 * t + 1];
        int s = c0 + c1;
        int inc = s;
#pragma unroll
        for (int d = 1; d < 64; d <<= 1) {
            int o = __shfl_up(inc, d);
            if (t >= d) inc += o;
        }
        int excl = inc - s;
        rbeg[2 * t] = excl;     lcur[2 * t] = excl;
        rbeg[2 * t + 1] = excl + c0; lcur[2 * t + 1] = excl + c0;
    }
    __syncthreads();
    for (int i = t; i < n; i += 1024) {
        unsigned u = sbuf[i];
        int pos = atomicAdd(&lcur[u >> 17], 1);
        csr[pos] = (int)(u & 0x1FFFFu);
    }
    __syncthreads();

    // ---- phase 4: fused node computation (r10-verified, LDS edge lists) ----
    int wid = t >> 6, lane = t & 63;
    int q = lane >> 4, ql = lane & 15;
    const _Float16* fh = (const _Float16*)fth;
#pragma unroll
    for (int k = 0; k < 8; ++k) {
        int ln = wid + 16 * k;                   // 16 waves x 8 nodes = 128
        int node = qq * Q_NODES + ln;
        int beg = rbeg[ln];
        int end = beg + cnt[ln];

        h4 rdv = (node < N_NODES)
                   ? *(const h4*)(fh + (size_t)node * OUT_F + 4 * ql) : (h4){0, 0, 0, 0};
        h2 dlo = __builtin_shufflevector(rdv, rdv, 0, 1);
        h2 dhi = __builtin_shufflevector(rdv, rdv, 2, 3);

        float m = -1e30f, l = 0.f;
        float a0 = 0.f, a1 = 0.f, a2 = 0.f, a3 = 0.f;

        for (int i = beg; i < end; i += 16) {
            int e0 = i + q, e1 = e0 + 4, e2 = e0 + 8, e3 = e0 + 12;
            bool u0 = e0 < end, u1 = e1 < end, u2 = e2 < end, u3 = e3 < end;
            int s0 = csr[u0 ? e0 : beg];
            int s1 = csr[u1 ? e1 : beg];
            int s2 = csr[u2 ? e2 : beg];
            int s3 = csr[u3 ? e3 : beg];
            h4 rA = *(const h4*)(fh + (size_t)s0 * OUT_F + 4 * ql);
            h4 rB = *(const h4*)(fh + (size_t)s1 * OUT_F + 4 * ql);
            h4 rC = *(const h4*)(fh + (size_t)s2 * OUT_F + 4 * ql);
            h4 rD = *(const h4*)(fh + (size_t)s3 * OUT_F + 4 * ql);

            float p0 = fdot2f(__builtin_shufflevector(rA, rA, 0, 1), dlo,
                       fdot2f(__builtin_shufflevector(rA, rA, 2, 3), dhi, 0.f));
            float p1 = fdot2f(__builtin_shufflevector(rB, rB, 0, 1), dlo,
                       fdot2f(__builtin_shufflevector(rB, rB, 2, 3), dhi, 0.f));
            float p2 = fdot2f(__builtin_shufflevector(rC, rC, 0, 1), dlo,
                       fdot2f(__builtin_shufflevector(rC, rC, 2, 3), dhi, 0.f));
            float p3 = fdot2f(__builtin_shufflevector(rD, rD, 0, 1), dlo,
                       fdot2f(__builtin_shufflevector(rD, rD, 2, 3), dhi, 0.f));
            REDUCE16(p0);
            REDUCE16(p1);
            REDUCE16(p2);
            REDUCE16(p3);
            p0 = u0 ? p0 * LOG2E : -1e30f;
            p1 = u1 ? p1 * LOG2E : -1e30f;
            p2 = u2 ? p2 * LOG2E : -1e30f;
            p3 = u3 ? p3 * LOG2E : -1e30f;

            // wave-uniform running max (pm reduced across all 64 lanes)
            float pm = fmaxf(fmaxf(p0, p1), fmaxf(p2, p3));
            pm = fmaxf(pm, __shfl_xor(pm, 16));
            pm = fmaxf(pm, __shfl_xor(pm, 32));
            if (pm > m) {                        // uniform branch: rescale only on growth
                float alpha = exp2f(m - pm);
                l *= alpha;
                a0 *= alpha; a1 *= alpha; a2 *= alpha; a3 *= alpha;
                m = pm;
            }
            float w0 = exp2f(p0 - m), w1 = exp2f(p1 - m);
            float w2 = exp2f(p2 - m), w3 = exp2f(p3 - m);
            l += (w0 + w1) + (w2 + w3);
#if __has_builtin(__builtin_amdgcn_cvt_pkrtz)
            h2 wlo = __builtin_bit_cast(h2, __builtin_amdgcn_cvt_pkrtz(w0, w1));
            h2 whi = __builtin_bit_cast(h2, __builtin_amdgcn_cvt_pkrtz(w2, w3));
#else
            h2 wlo = {(_Float16)w0, (_Float16)w1};
            h2 whi = {(_Float16)w2, (_Float16)w3};
#endif
            h2 cab0 = {rA[0], rB[0]}, ccd0 = {rC[0], rD[0]};
            h2 cab1 = {rA[1], rB[1]}, ccd1 = {rC[1], rD[1]};
            h2 cab2 = {rA[2], rB[2]}, ccd2 = {rC[2], rD[2]};
            h2 cab3 = {rA[3], rB[3]}, ccd3 = {rC[3], rD[3]};
            a0 = fdot2f(wlo, cab0, fdot2f(whi, ccd0, a0));
            a1 = fdot2f(wlo, cab1, fdot2f(whi, ccd1, a1));
            a2 = fdot2f(wlo, cab2, fdot2f(whi, ccd2, a2));
            a3 = fdot2f(wlo, cab3, fdot2f(whi, ccd3, a3));
        }

        // m is wave-uniform: quarter merge is a plain sum (no exp2/rescale)
#pragma unroll
        for (int dd = 16; dd <= 32; dd <<= 1) {
            l  += __shfl_xor(l, dd);
            a0 += __shfl_xor(a0, dd);
            a1 += __shfl_xor(a1, dd);
            a2 += __shfl_xor(a2, dd);
            a3 += __shfl_xor(a3, dd);
        }
        if (q == 0 && node < N_NODES) {
            float inv = (l > 0.f) ? 1.f / l : 0.f;
            *(float4*)(out + (size_t)node * OUT_F + 4 * ql) =
                make_float4(a0 * inv, a1 * inv, a2 * inv, a3 * inv);
        }
    }
}

extern "C" void kernel_launch(void* const* d_in, const int* in_sizes, int n_in,
                              void* d_out, int out_size, void* d_ws, size_t ws_size,
                              hipStream_t stream) {
    const float* feat = (const float*)d_in[0];
    const float* W    = (const float*)d_in[1];
    const int*   src  = (const int*)d_in[2];
    const int*   dst  = (const int*)d_in[3];
    float* out = (float*)d_out;

    __half*   fth      = (__half*)d_ws;
    unsigned* staging  = (unsigned*)((int*)d_ws + (size_t)N_NODES * OUT_F / 2);
    unsigned* pmeta    = staging + (size_t)PBLKS * CHUNK;

    partition_linear_kernel<<<PBLKS + LBLKS, 256, 0, stream>>>(src, dst, staging, pmeta,
                                                               feat, W, fth);
    quarter_fused_kernel<<<NQ, 1024, 0, stream>>>(staging, pmeta, fth, out);
}